// Round 20
// baseline (57.152 us; speedup 1.0000x reference)
//
#include <hip/hip_runtime.h>

typedef _Float16 f16;
typedef _Float16 f16x4 __attribute__((ext_vector_type(4)));
typedef _Float16 f16x8 __attribute__((ext_vector_type(8)));
typedef __fp16 fp16x2 __attribute__((ext_vector_type(2)));   // cvt_pkrtz native type
typedef float f32x4 __attribute__((ext_vector_type(4)));

#define MFMA_16x16x32_F16(A, B, C) __builtin_amdgcn_mfma_f32_16x16x32_f16((A), (B), (C), 0, 0, 0)

typedef const __attribute__((address_space(1))) char gchar;
typedef __attribute__((address_space(3))) char lchar;

__device__ __forceinline__ float fexp2(float x) { return __builtin_amdgcn_exp2f(x); }
__device__ __forceinline__ int swzb(int b) { return b ^ ((b >> 3) & 0x70); }  // involution, 8KB-tile-local

namespace {
constexpr int SB = 4096;                       // tokens per flattened batch = 64 tiles of 64
constexpr size_t BB = (size_t)SB * 64 * 2;     // f16 bytes per batch per tensor = 512KB
}

// V-ONLY token permutation within each 64-token tile (K stays identity!):
//   V^T stored slot n holds token kappa_V(n), kappa_V(32kt+8g+4a+v)=32kt+16a+4g+v.
//   PV's B-fragment slot 32kt+8g+j then needs exactly the lane's own QK^T output
//   e[8kt+j], so P never leaves registers.
__device__ __forceinline__ int kinv(int r) {
    return 32 * (r >> 5) + 8 * ((r >> 2) & 3) + 4 * ((r >> 4) & 1) + (r & 3);
}

// ---------------- pre-pass: gather + fp16 convert + V tile-transpose ----------------
// Stores PRE-SWIZZLED within each 8KB tile; V additionally kappa_V-permuted in token axis.
__global__ __launch_bounds__(256)
void hilbert_prepass_kernel(const float* __restrict__ kp, const float* __restrict__ vp,
                            const int* __restrict__ perm,
                            char* __restrict__ kw, char* __restrict__ vtw)
{
    const int bid = blockIdx.x;
    const int batch = bid & 7;
    const int tile = bid >> 3;
    const int tid = (int)threadIdx.x;
    const int r = tid >> 2;       // token in tile
    const int c4 = tid & 3;       // 16-dim quarter

    __shared__ float Vl[64][68];  // fp32 V tile, padded

    const int t = tile * 64 + r;
    const int srow = perm[batch * 512 + (t >> 3)];
    const size_t boff = (size_t)srow * 512 + (t & 7) * 64 + c4 * 16;

    {   // K -> fp16, IDENTITY row placement, swizzled store
        const float* ks = kp + boff;
        const float4 k0 = *(const float4*)(ks + 0);
        const float4 k1 = *(const float4*)(ks + 4);
        const float4 k2 = *(const float4*)(ks + 8);
        const float4 k3 = *(const float4*)(ks + 12);
        f16x8 h0, h1;
        h0[0] = (f16)k0.x; h0[1] = (f16)k0.y; h0[2] = (f16)k0.z; h0[3] = (f16)k0.w;
        h0[4] = (f16)k1.x; h0[5] = (f16)k1.y; h0[6] = (f16)k1.z; h0[7] = (f16)k1.w;
        h1[0] = (f16)k2.x; h1[1] = (f16)k2.y; h1[2] = (f16)k2.z; h1[3] = (f16)k2.w;
        h1[4] = (f16)k3.x; h1[5] = (f16)k3.y; h1[6] = (f16)k3.z; h1[7] = (f16)k3.w;
        char* kt = kw + (size_t)batch * BB + (size_t)tile * 8192;
        const int o = r * 128 + c4 * 32;
        *(f16x8*)(kt + swzb(o)) = h0;
        *(f16x8*)(kt + swzb(o + 16)) = h1;
    }
    {   // V fp32 -> LDS
        const float* vs = vp + boff;
        *(float4*)&Vl[r][c4 * 16 + 0]  = *(const float4*)(vs + 0);
        *(float4*)&Vl[r][c4 * 16 + 4]  = *(const float4*)(vs + 4);
        *(float4*)&Vl[r][c4 * 16 + 8]  = *(const float4*)(vs + 8);
        *(float4*)&Vl[r][c4 * 16 + 12] = *(const float4*)(vs + 12);
    }
    __syncthreads();
    {   // transpose out of LDS: thread owns dim d, tokens 16a..16a+15; kappa_V cols
        const int d = tid >> 2;
        const int a = tid & 3;
        char* vt = vtw + (size_t)batch * BB + (size_t)tile * 8192;
        const int b0 = 32 * (a >> 1) + 4 * (a & 1);
#pragma unroll
        for (int gp = 0; gp < 4; ++gp) {
            f16x4 qv;
#pragma unroll
            for (int v = 0; v < 4; ++v) qv[v] = (f16)Vl[16 * a + 4 * gp + v][d];
            *(f16x4*)(vt + swzb(d * 128 + (b0 + 8 * gp) * 2)) = qv;
        }
    }
}

// ---------------- main attention ----------------
// 256 blocks (1/CU) x 512 threads = 8 waves = wq(4) x half(2); wave owns 32 q-rows
// (two 16-row subtiles sharing every K/V fragment read); half takes its half-tile.
// FINE-PHASE (8-phase-style) body: each tile n = 4 short phases, each
//   {(stage issue) + 4 ds_reads (+exp2 slice in P3/P4) -> s_barrier ->
//    setprio(1) -> 8 MFMA -> setprio(0) -> s_barrier}.
// Staging leads by TWO tiles into a 3-buffer rotation (96KB); ONE counted
// vmcnt(4) per tile at P4 confirms tile n+1, leaving tile n+2's loads in
// flight. Never vmcnt(0) until the tail. (T3+T4 regime per catalog: coarse
// 2-phase bodies null every technique; the fine interleave is the documented
// prerequisite — r9-r18 were all 2-phase.)
// NO-MAX softmax; P in registers (V-kappa layout).
__global__ __launch_bounds__(512, 2)
void hilbert_attn_kernel(const float* __restrict__ qp,
                         const int* __restrict__ perm,
                         const char* __restrict__ kw, const char* __restrict__ vtw,
                         float* __restrict__ op)
{
    __shared__ __align__(16) char SM[98304];   // 3 bufs x {K 16KB | V 16KB}

    const int bid = blockIdx.x;
    const int batch = bid & 7;            // XCD-affine: one batch per XCD
    const int qbase = (bid >> 3) * 128;
    const int tid = (int)threadIdx.x;
    const int w = tid >> 6;
    const int lane = tid & 63;
    const int l16 = lane & 15;
    const int g = lane >> 4;
    const int half = w >> 2;
    const int wq = w & 3;
    const int swz = (l16 & 7) << 4;

    const f32x4 Z4 = {0.f, 0.f, 0.f, 0.f};

    // Q B-fragments for both 16-row slots; scale*log2e folded
    f16x8 Qf0[2], Qf1[2];
    {
        constexpr float qscl = 0.125f * 1.44269504088896340736f;
#pragma unroll
        for (int s = 0; s < 2; ++s) {
            const int t = qbase + wq * 32 + s * 16 + l16;
            const int srow = perm[batch * 512 + (t >> 3)];
            const float* src = qp + (size_t)srow * 512 + (t & 7) * 64 + g * 8;
#pragma unroll
            for (int kt = 0; kt < 2; ++kt) {
                const float4 x0 = *(const float4*)(src + 32 * kt);
                const float4 x1 = *(const float4*)(src + 32 * kt + 4);
                f16x8 f;
                f[0] = (f16)(x0.x * qscl); f[1] = (f16)(x0.y * qscl);
                f[2] = (f16)(x0.z * qscl); f[3] = (f16)(x0.w * qscl);
                f[4] = (f16)(x1.x * qscl); f[5] = (f16)(x1.y * qscl);
                f[6] = (f16)(x1.z * qscl); f[7] = (f16)(x1.w * qscl);
                if (s == 0) Qf0[kt] = f; else Qf1[kt] = f;
            }
        }
    }

    f32x4 oacc0[4], oacc1[4];
#pragma unroll
    for (int i = 0; i < 4; ++i) {
        oacc0[i] = Z4;
        oacc1[i] = Z4;
    }
    float lr0 = 0.f, lr1 = 0.f;

    const char* ksrc = kw + (size_t)batch * BB + (size_t)tid * 16;
    const char* vsrc = vtw + (size_t)batch * BB + (size_t)tid * 16;

    union U8 { f16x8 v; fp16x2 h[4]; };

#define STAGE_K(buf3, p)                                                             \
    do {                                                                             \
        lchar* d_ = (lchar*)&SM[(buf3) * 32768 + (w << 10)];                         \
        const char* s_ = ksrc + (size_t)(p) * 16384;                                 \
        __builtin_amdgcn_global_load_lds((gchar*)(s_), d_, 16, 0, 0);                \
        __builtin_amdgcn_global_load_lds((gchar*)(s_ + 8192), d_ + 8192, 16, 0, 0);  \
    } while (0)
#define STAGE_V(buf3, p)                                                             \
    do {                                                                             \
        lchar* d_ = (lchar*)&SM[(buf3) * 32768 + 16384 + (w << 10)];                 \
        const char* s_ = vsrc + (size_t)(p) * 16384;                                 \
        __builtin_amdgcn_global_load_lds((gchar*)(s_), d_, 16, 0, 0);                \
        __builtin_amdgcn_global_load_lds((gchar*)(s_ + 8192), d_ + 8192, 16, 0, 0);  \
    } while (0)

    // prologue: stage tiles 0 and 1; confirm 0, leave 1 in flight
    STAGE_K(0, 0); STAGE_V(0, 0);
    STAGE_K(1, 1); STAGE_V(1, 1);
    asm volatile("s_waitcnt vmcnt(4)" ::: "memory");   // K0,V0 confirmed
    __builtin_amdgcn_s_barrier();

    for (int n = 0; n < 32; ++n) {
        const int bn = n % 3;
        const int kbb = bn * 32768 + half * 8192;
        const int vbb = kbb + 16384;
        const int b2 = (bn + 2) % 3;            // (n+2)%3
        const bool st = (n < 30);

        f32x4 sa0[4], sa1[4];

        // ---- P1: issue K(n+2); read K(n) kt=0; bar; 8 MFMA; bar ----
        if (st) STAGE_K(b2, n + 2);
        {
            f16x8 kf[4];
#pragma unroll
            for (int mt = 0; mt < 4; ++mt)
                kf[mt] = *(const f16x8*)&SM[kbb + (l16 + 16 * mt) * 128 + ((g * 16) ^ swz)];
            __builtin_amdgcn_s_barrier();
            __builtin_amdgcn_s_setprio(1);
#pragma unroll
            for (int mt = 0; mt < 4; ++mt) {
                sa0[mt] = MFMA_16x16x32_F16(kf[mt], Qf0[0], Z4);
                sa1[mt] = MFMA_16x16x32_F16(kf[mt], Qf1[0], Z4);
            }
            __builtin_amdgcn_s_setprio(0);
            __builtin_amdgcn_s_barrier();
        }

        // ---- P2: read K(n) kt=1; bar; 8 MFMA; bar ----
        {
            f16x8 kf[4];
#pragma unroll
            for (int mt = 0; mt < 4; ++mt)
                kf[mt] = *(const f16x8*)&SM[kbb + (l16 + 16 * mt) * 128 + (((g + 4) * 16) ^ swz)];
            __builtin_amdgcn_s_barrier();
            __builtin_amdgcn_s_setprio(1);
#pragma unroll
            for (int mt = 0; mt < 4; ++mt) {
                sa0[mt] = MFMA_16x16x32_F16(kf[mt], Qf0[1], sa0[mt]);
                sa1[mt] = MFMA_16x16x32_F16(kf[mt], Qf1[1], sa1[mt]);
            }
            __builtin_amdgcn_s_setprio(0);
            __builtin_amdgcn_s_barrier();
        }

        // ---- P3: issue V(n+2); exp2 mt=0,1 -> pf0; read V kt=0; bar; 8 MFMA PV; bar ----
        U8 p0k0, p1k0, p0k1, p1k1;
        if (st) STAGE_V(b2, n + 2);
        {
#pragma unroll
            for (int mt = 0; mt < 2; ++mt) {
                const float a0 = fexp2(sa0[mt][0]);
                const float a1 = fexp2(sa0[mt][1]);
                const float a2 = fexp2(sa0[mt][2]);
                const float a3 = fexp2(sa0[mt][3]);
                lr0 += (a0 + a1) + (a2 + a3);
                p0k0.h[2 * mt]     = __builtin_amdgcn_cvt_pkrtz(a0, a1);
                p0k0.h[2 * mt + 1] = __builtin_amdgcn_cvt_pkrtz(a2, a3);
                const float b0 = fexp2(sa1[mt][0]);
                const float b1 = fexp2(sa1[mt][1]);
                const float b2_ = fexp2(sa1[mt][2]);
                const float b3 = fexp2(sa1[mt][3]);
                lr1 += (b0 + b1) + (b2_ + b3);
                p1k0.h[2 * mt]     = __builtin_amdgcn_cvt_pkrtz(b0, b1);
                p1k0.h[2 * mt + 1] = __builtin_amdgcn_cvt_pkrtz(b2_, b3);
            }
            f16x8 vf[4];
#pragma unroll
            for (int mtd = 0; mtd < 4; ++mtd)
                vf[mtd] = *(const f16x8*)&SM[vbb + (l16 + 16 * mtd) * 128 + ((g * 16) ^ swz)];
            __builtin_amdgcn_s_barrier();
            __builtin_amdgcn_s_setprio(1);
#pragma unroll
            for (int mtd = 0; mtd < 4; ++mtd) {
                oacc0[mtd] = MFMA_16x16x32_F16(vf[mtd], p0k0.v, oacc0[mtd]);
                oacc1[mtd] = MFMA_16x16x32_F16(vf[mtd], p1k0.v, oacc1[mtd]);
            }
            __builtin_amdgcn_s_setprio(0);
            __builtin_amdgcn_s_barrier();
        }

        // ---- P4: exp2 mt=2,3 -> pf1; read V kt=1; vmcnt(4); bar; 8 MFMA PV; bar ----
        {
#pragma unroll
            for (int mt = 2; mt < 4; ++mt) {
                const float a0 = fexp2(sa0[mt][0]);
                const float a1 = fexp2(sa0[mt][1]);
                const float a2 = fexp2(sa0[mt][2]);
                const float a3 = fexp2(sa0[mt][3]);
                lr0 += (a0 + a1) + (a2 + a3);
                p0k1.h[2 * (mt - 2)]     = __builtin_amdgcn_cvt_pkrtz(a0, a1);
                p0k1.h[2 * (mt - 2) + 1] = __builtin_amdgcn_cvt_pkrtz(a2, a3);
                const float b0 = fexp2(sa1[mt][0]);
                const float b1 = fexp2(sa1[mt][1]);
                const float b2_ = fexp2(sa1[mt][2]);
                const float b3 = fexp2(sa1[mt][3]);
                lr1 += (b0 + b1) + (b2_ + b3);
                p1k1.h[2 * (mt - 2)]     = __builtin_amdgcn_cvt_pkrtz(b0, b1);
                p1k1.h[2 * (mt - 2) + 1] = __builtin_amdgcn_cvt_pkrtz(b2_, b3);
            }
            f16x8 vf[4];
#pragma unroll
            for (int mtd = 0; mtd < 4; ++mtd)
                vf[mtd] = *(const f16x8*)&SM[vbb + (l16 + 16 * mtd) * 128 + (((g + 4) * 16) ^ swz)];
            // counted wait: confirm tile n+1 (K,V); leave tile n+2's 4 loads in flight
            if (n < 30)       { asm volatile("s_waitcnt vmcnt(4)" ::: "memory"); }
            else if (n == 30) { asm volatile("s_waitcnt vmcnt(0)" ::: "memory"); }
            __builtin_amdgcn_s_barrier();
            __builtin_amdgcn_s_setprio(1);
#pragma unroll
            for (int mtd = 0; mtd < 4; ++mtd) {
                oacc0[mtd] = MFMA_16x16x32_F16(vf[mtd], p0k1.v, oacc0[mtd]);
                oacc1[mtd] = MFMA_16x16x32_F16(vf[mtd], p1k1.v, oacc1[mtd]);
            }
            __builtin_amdgcn_s_setprio(0);
            __builtin_amdgcn_s_barrier();
        }
    }
#undef STAGE_K
#undef STAGE_V

    // ---- reduce l across the 4 key-groups of each wave ----
    lr0 += __shfl_xor(lr0, 16);
    lr0 += __shfl_xor(lr0, 32);
    lr1 += __shfl_xor(lr1, 16);
    lr1 += __shfl_xor(lr1, 32);

    __syncthreads();   // loop done (vmcnt drained at n=30); reuse SM for merge

    // ---- merge wave pairs (w, w+4): l = la+lb, O = Oa+Ob ----
    float* OB = (float*)SM;                 // 4 pairs x 8KB (32 rows x 64 dims)
    float* ML = (float*)&SM[32768];         // 4 pairs x 32 l-values
    if (w >= 4) {
        float* ob = OB + wq * 2048;
#pragma unroll
        for (int mtd = 0; mtd < 4; ++mtd) {
            *(f32x4*)&ob[l16 * 64 + mtd * 16 + g * 4] = oacc0[mtd];
            *(f32x4*)&ob[(16 + l16) * 64 + mtd * 16 + g * 4] = oacc1[mtd];
        }
        if (g == 0) {
            ML[wq * 32 + l16] = lr0;
            ML[wq * 32 + 16 + l16] = lr1;
        }
    }
    __syncthreads();
    if (w < 4) {
        float* ob = OB + wq * 2048;
#pragma unroll
        for (int s = 0; s < 2; ++s) {
            const float lmine = (s == 0) ? lr0 : lr1;
            const float linv = 1.f / (lmine + ML[wq * 32 + s * 16 + l16]);
            const int t = qbase + wq * 32 + s * 16 + l16;
            const int srow = perm[t];       // scatter uses FULL-t perm (round-1 lesson)
            float* dst = op + (size_t)srow * 512 + batch * 64 + 4 * g;
#pragma unroll
            for (int mtd = 0; mtd < 4; ++mtd) {
                const f32x4 mine = (s == 0) ? oacc0[mtd] : oacc1[mtd];
                const f32x4 o2 = *(const f32x4*)&ob[(s * 16 + l16) * 64 + mtd * 16 + g * 4];
                float4 o;
                o.x = (mine[0] + o2[0]) * linv;
                o.y = (mine[1] + o2[1]) * linv;
                o.z = (mine[2] + o2[2]) * linv;
                o.w = (mine[3] + o2[3]) * linv;
                *(float4*)(dst + 16 * mtd) = o;
            }
        }
    }
}

extern "C" void kernel_launch(void* const* d_in, const int* in_sizes, int n_in,
                              void* d_out, int out_size, void* d_ws, size_t ws_size,
                              hipStream_t stream) {
    (void)in_sizes; (void)n_in; (void)out_size; (void)ws_size;
    const float* q = (const float*)d_in[0];
    const float* k = (const float*)d_in[1];
    const float* v = (const float*)d_in[2];
    const int* perm = (const int*)d_in[3];
    float* out = (float*)d_out;
    char* kw = (char*)d_ws;          // 4MB
    char* vtw = kw + 8 * BB;         // 4MB
    hipLaunchKernelGGL(hilbert_prepass_kernel, dim3(512), dim3(256), 0, stream,
                       k, v, perm, kw, vtw);
    hipLaunchKernelGGL(hilbert_attn_kernel, dim3(256), dim3(512), 0, stream,
                       q, perm, kw, vtw, out);
}

// Round 21
// 54.233 us; speedup vs baseline: 1.0538x; 1.0538x over previous
//
#include <hip/hip_runtime.h>

typedef _Float16 f16;
typedef _Float16 f16x4 __attribute__((ext_vector_type(4)));
typedef _Float16 f16x8 __attribute__((ext_vector_type(8)));
typedef __fp16 fp16x2 __attribute__((ext_vector_type(2)));   // cvt_pkrtz native type
typedef float f32x4 __attribute__((ext_vector_type(4)));
typedef float f32x16 __attribute__((ext_vector_type(16)));

#define MFMA32(A, B, C) __builtin_amdgcn_mfma_f32_32x32x16_f16((A), (B), (C), 0, 0, 0)

typedef const __attribute__((address_space(1))) char gchar;
typedef __attribute__((address_space(3))) char lchar;

__device__ __forceinline__ float fexp2(float x) { return __builtin_amdgcn_exp2f(x); }
__device__ __forceinline__ int swzb(int b) { return b ^ ((b >> 3) & 0x70); }  // involution: XOR (row&7)<<4

namespace {
constexpr int SB = 4096;                       // tokens per flattened batch = 64 tiles of 64
constexpr size_t BB = (size_t)SB * 64 * 2;     // f16 bytes per batch per tensor = 512KB
}

// 32x32x16 MFMA layouts (A: row=l&31,k=8*(l>>5)+j; C/D: col=l&31,row=(reg&3)+8(reg>>2)+4hi).
// V-ONLY slot permutation per 32-token granule: slot n=16s+8hi+4j2+j1 holds token
// j1+8j2+16s+4hi. Then PV's B-fragment for K=16 step s is exactly pack(e[8s..8s+7])
// of the lane's own QK^T outputs (K stored IDENTITY) — P never leaves registers.

// ---------------- pre-pass: gather + fp16 convert + V tile-transpose ----------------
__global__ __launch_bounds__(256)
void hilbert_prepass_kernel(const float* __restrict__ kp, const float* __restrict__ vp,
                            const int* __restrict__ perm,
                            char* __restrict__ kw, char* __restrict__ vtw)
{
    const int bid = blockIdx.x;
    const int batch = bid & 7;
    const int tile = bid >> 3;
    const int tid = (int)threadIdx.x;
    const int r = tid >> 2;       // token in tile
    const int c4 = tid & 3;       // 16-dim quarter

    __shared__ float Vl[64][68];  // fp32 V tile, padded

    const int t = tile * 64 + r;
    const int srow = perm[batch * 512 + (t >> 3)];
    const size_t boff = (size_t)srow * 512 + (t & 7) * 64 + c4 * 16;

    {   // K -> fp16, IDENTITY row placement, swizzled store
        const float* ks = kp + boff;
        const float4 k0 = *(const float4*)(ks + 0);
        const float4 k1 = *(const float4*)(ks + 4);
        const float4 k2 = *(const float4*)(ks + 8);
        const float4 k3 = *(const float4*)(ks + 12);
        f16x8 h0, h1;
        h0[0] = (f16)k0.x; h0[1] = (f16)k0.y; h0[2] = (f16)k0.z; h0[3] = (f16)k0.w;
        h0[4] = (f16)k1.x; h0[5] = (f16)k1.y; h0[6] = (f16)k1.z; h0[7] = (f16)k1.w;
        h1[0] = (f16)k2.x; h1[1] = (f16)k2.y; h1[2] = (f16)k2.z; h1[3] = (f16)k2.w;
        h1[4] = (f16)k3.x; h1[5] = (f16)k3.y; h1[6] = (f16)k3.z; h1[7] = (f16)k3.w;
        char* kt = kw + (size_t)batch * BB + (size_t)tile * 8192;
        const int o = r * 128 + c4 * 32;
        *(f16x8*)(kt + swzb(o)) = h0;
        *(f16x8*)(kt + swzb(o + 16)) = h1;
    }
    {   // V fp32 -> LDS
        const float* vs = vp + boff;
        *(float4*)&Vl[r][c4 * 16 + 0]  = *(const float4*)(vs + 0);
        *(float4*)&Vl[r][c4 * 16 + 4]  = *(const float4*)(vs + 4);
        *(float4*)&Vl[r][c4 * 16 + 8]  = *(const float4*)(vs + 8);
        *(float4*)&Vl[r][c4 * 16 + 12] = *(const float4*)(vs + 12);
    }
    __syncthreads();
    {   // transpose: thread owns dim d, tokens 16a..16a+15; 32x32-kappa slots
        // token T=16a+4gp+v -> slot 32*(a>>1) + 16*(a&1) + 8*(gp&1) + 4*(gp>>1) + v
        const int d = tid >> 2;
        const int a = tid & 3;
        char* vt = vtw + (size_t)batch * BB + (size_t)tile * 8192;
        const int sbase = 32 * (a >> 1) + 16 * (a & 1);
#pragma unroll
        for (int gp = 0; gp < 4; ++gp) {
            f16x4 qv;
#pragma unroll
            for (int v = 0; v < 4; ++v) qv[v] = (f16)Vl[16 * a + 4 * gp + v][d];
            const int slot = sbase + 8 * (gp & 1) + 4 * (gp >> 1);
            *(f16x4*)(vt + swzb(d * 128 + slot * 2)) = qv;
        }
    }
}

// ---------------- main attention ----------------
// 256 blocks (1/CU) x 512 threads = 8 waves = wq(4) x half(2); wave owns 32 q-rows
// via 32x32x16 MFMA (one 32-row fragment, NOT two 16-row slots); half takes its
// 64-key tile per iteration. 16 MFMA/tile/wave (was 32 of 16x16x32) at the 15%-
// faster 32x32 rate. NO-MAX softmax; P in registers (32x32 V-kappa layout).
// r14's proven counted-vmcnt 2-buffer schedule, tail peeled.
__global__ __launch_bounds__(512, 2)
void hilbert_attn_kernel(const float* __restrict__ qp,
                         const int* __restrict__ perm,
                         const char* __restrict__ kw, const char* __restrict__ vtw,
                         float* __restrict__ op)
{
    __shared__ __align__(16) char SM[65536];

    const int bid = blockIdx.x;
    const int batch = bid & 7;            // XCD-affine: one batch per XCD
    const int qbase = (bid >> 3) * 128;
    const int tid = (int)threadIdx.x;
    const int w = tid >> 6;
    const int lane = tid & 63;
    const int l5 = lane & 31;
    const int hi = lane >> 5;
    const int swz = (lane & 7) << 4;
    const int half = w >> 2;
    const int wq = w & 3;

    const f32x16 Z16 = {0.f, 0.f, 0.f, 0.f, 0.f, 0.f, 0.f, 0.f,
                        0.f, 0.f, 0.f, 0.f, 0.f, 0.f, 0.f, 0.f};

    // Q B-fragments: lane holds Q[q=l5][d = 16*step + 8*hi + j]; scale*log2e folded
    f16x8 Qf[4];
    {
        constexpr float qscl = 0.125f * 1.44269504088896340736f;
        const int t = qbase + wq * 32 + l5;
        const int srow = perm[batch * 512 + (t >> 3)];
        const float* src = qp + (size_t)srow * 512 + (t & 7) * 64 + 8 * hi;
#pragma unroll
        for (int step = 0; step < 4; ++step) {
            const float4 x0 = *(const float4*)(src + 16 * step);
            const float4 x1 = *(const float4*)(src + 16 * step + 4);
            f16x8 f;
            f[0] = (f16)(x0.x * qscl); f[1] = (f16)(x0.y * qscl);
            f[2] = (f16)(x0.z * qscl); f[3] = (f16)(x0.w * qscl);
            f[4] = (f16)(x1.x * qscl); f[5] = (f16)(x1.y * qscl);
            f[6] = (f16)(x1.z * qscl); f[7] = (f16)(x1.w * qscl);
            Qf[step] = f;
        }
    }

    f32x16 oacc[2];
    oacc[0] = Z16; oacc[1] = Z16;
    float lr = 0.f;

    const char* ksrc = kw + (size_t)batch * BB + (size_t)tid * 16;
    const char* vsrc = vtw + (size_t)batch * BB + (size_t)tid * 16;

    union U8 { f16x8 v; fp16x2 h[4]; };

#define STAGE_K(dstbuf, p)                                                           \
    do {                                                                             \
        lchar* d_ = (lchar*)&SM[(dstbuf) * 32768 + (w << 10)];                       \
        const char* s_ = ksrc + (size_t)(p) * 16384;                                 \
        __builtin_amdgcn_global_load_lds((gchar*)(s_), d_, 16, 0, 0);                \
        __builtin_amdgcn_global_load_lds((gchar*)(s_ + 8192), d_ + 8192, 16, 0, 0);  \
    } while (0)
#define STAGE_V(dstbuf, p)                                                           \
    do {                                                                             \
        lchar* d_ = (lchar*)&SM[(dstbuf) * 32768 + 16384 + (w << 10)];               \
        const char* s_ = vsrc + (size_t)(p) * 16384;                                 \
        __builtin_amdgcn_global_load_lds((gchar*)(s_), d_, 16, 0, 0);                \
        __builtin_amdgcn_global_load_lds((gchar*)(s_ + 8192), d_ + 8192, 16, 0, 0);  \
    } while (0)

#define QK_GRANULE(dst, kbb_, h2)                                                    \
    do {                                                                             \
        dst = Z16;                                                                   \
        _Pragma("unroll")                                                            \
        for (int step = 0; step < 4; ++step) {                                       \
            const int off = (kbb_) + (32 * (h2) + l5) * 128 +                        \
                            ((32 * step + 16 * hi) ^ swz);                           \
            const f16x8 kf = *(const f16x8*)&SM[off];                                \
            dst = MFMA32(kf, Qf[step], dst);                                         \
        }                                                                            \
    } while (0)

#define SOFTMAX_GRANULE(sa, p0, p1)                                                  \
    do {                                                                             \
        float e_[16];                                                                \
        _Pragma("unroll")                                                            \
        for (int j = 0; j < 16; ++j) e_[j] = fexp2((sa)[j]);                         \
        _Pragma("unroll")                                                            \
        for (int j = 0; j < 16; ++j) lr += e_[j];                                    \
        _Pragma("unroll")                                                            \
        for (int i = 0; i < 4; ++i) {                                                \
            (p0).h[i] = __builtin_amdgcn_cvt_pkrtz(e_[2 * i], e_[2 * i + 1]);        \
            (p1).h[i] = __builtin_amdgcn_cvt_pkrtz(e_[8 + 2 * i], e_[9 + 2 * i]);    \
        }                                                                            \
    } while (0)

#define PV_GRANULE(vbb_, h2, p0, p1)                                                 \
    do {                                                                             \
        _Pragma("unroll")                                                            \
        for (int s = 0; s < 2; ++s) {                                                \
            const f16x8 pf = s ? (p1).v : (p0).v;                                    \
            _Pragma("unroll")                                                        \
            for (int mf = 0; mf < 2; ++mf) {                                         \
                const int voff = (vbb_) + (32 * mf + l5) * 128 +                     \
                                 ((64 * (h2) + 32 * s + 16 * hi) ^ swz);             \
                const f16x8 vf = *(const f16x8*)&SM[voff];                           \
                oacc[mf] = MFMA32(vf, pf, oacc[mf]);                                 \
            }                                                                        \
        }                                                                            \
    } while (0)

    {   // prologue: stage tile-pair 0 (2K + 2V = 32KB) into buffer 0, drain once
        lchar* dst = (lchar*)&SM[w << 10];
        __builtin_amdgcn_global_load_lds((gchar*)(ksrc), dst, 16, 0, 0);
        __builtin_amdgcn_global_load_lds((gchar*)(ksrc + 8192), dst + 8192, 16, 0, 0);
        __builtin_amdgcn_global_load_lds((gchar*)(vsrc), dst + 16384, 16, 0, 0);
        __builtin_amdgcn_global_load_lds((gchar*)(vsrc + 8192), dst + 24576, 16, 0, 0);
    }
    asm volatile("s_waitcnt vmcnt(0)" ::: "memory");
    __builtin_amdgcn_s_barrier();

    for (int it = 0; it < 31; ++it) {
        const int cur = it & 1;
        const int kbb = cur * 32768 + half * 8192;
        const int vbb = cur * 32768 + 16384 + half * 8192;

        STAGE_K(cur ^ 1, it + 1);   // K(next) in flight across the mid barrier

        // ---- QK both granules (8 MFMA) ----
        f32x16 sa0, sa1;
        __builtin_amdgcn_s_setprio(1);
        QK_GRANULE(sa0, kbb, 0);
        QK_GRANULE(sa1, kbb, 1);
        __builtin_amdgcn_s_setprio(0);

        STAGE_V(cur ^ 1, it + 1);   // V(next), confirmed at NEXT iter's mid barrier

        // ---- no-max softmax, P packed to registers ----
        U8 pa0, pa1, pb0, pb1;
        SOFTMAX_GRANULE(sa0, pa0, pa1);
        SOFTMAX_GRANULE(sa1, pb0, pb1);

        // mid barrier: V(cur) confirmed; K(next)/V(next) stay in flight
        asm volatile("s_waitcnt vmcnt(4)" ::: "memory");
        __builtin_amdgcn_s_barrier();

        // ---- PV both granules (8 MFMA) ----
        __builtin_amdgcn_s_setprio(1);
        PV_GRANULE(vbb, 0, pa0, pa1);
        PV_GRANULE(vbb, 1, pb0, pb1);
        __builtin_amdgcn_s_setprio(0);

        // end barrier: K(next) confirmed; V(next) stays in flight
        asm volatile("s_waitcnt vmcnt(2)" ::: "memory");
        __builtin_amdgcn_s_barrier();
    }

    {   // ---- tail iteration it=31 (buffer 1; outstanding at entry: [V31 2]) ----
        const int kbb = 32768 + half * 8192;
        const int vbb = 32768 + 16384 + half * 8192;
        f32x16 sa0, sa1;
        QK_GRANULE(sa0, kbb, 0);
        QK_GRANULE(sa1, kbb, 1);
        U8 pa0, pa1, pb0, pb1;
        SOFTMAX_GRANULE(sa0, pa0, pa1);
        SOFTMAX_GRANULE(sa1, pb0, pb1);
        asm volatile("s_waitcnt vmcnt(0)" ::: "memory");
        __builtin_amdgcn_s_barrier();
        PV_GRANULE(vbb, 0, pa0, pa1);
        PV_GRANULE(vbb, 1, pb0, pb1);
    }
#undef STAGE_K
#undef STAGE_V
#undef QK_GRANULE
#undef SOFTMAX_GRANULE
#undef PV_GRANULE

    // ---- l reduce: lanes (l, l+32) cover complementary key subsets of q=l5 ----
    lr += __shfl_xor(lr, 32);

    __syncthreads();   // loop done; reuse SM for merge

    // ---- merge wave pairs (w, w+4): l = la+lb, O = Oa+Ob ----
    float* OB = (float*)SM;                 // 4 pairs x 8KB (32 rows x 64 dims)
    float* ML = (float*)&SM[32768];         // 4 pairs x 32 l-values
    if (w >= 4) {
        float* ob = OB + wq * 2048;
#pragma unroll
        for (int mf = 0; mf < 2; ++mf)
#pragma unroll
            for (int q2 = 0; q2 < 4; ++q2) {
                f32x4 v;
                v[0] = oacc[mf][4 * q2 + 0]; v[1] = oacc[mf][4 * q2 + 1];
                v[2] = oacc[mf][4 * q2 + 2]; v[3] = oacc[mf][4 * q2 + 3];
                *(f32x4*)&ob[l5 * 64 + 32 * mf + 8 * q2 + 4 * hi] = v;
            }
        if (hi == 0) ML[wq * 32 + l5] = lr;
    }
    __syncthreads();
    if (w < 4) {
        float* ob = OB + wq * 2048;
        const float linv = 1.f / (lr + ML[wq * 32 + l5]);
        const int t = qbase + wq * 32 + l5;
        const int srow = perm[t];           // scatter uses FULL-t perm (round-1 lesson)
        float* dst = op + (size_t)srow * 512 + batch * 64;
#pragma unroll
        for (int mf = 0; mf < 2; ++mf)
#pragma unroll
            for (int q2 = 0; q2 < 4; ++q2) {
                const f32x4 o2 = *(const f32x4*)&ob[l5 * 64 + 32 * mf + 8 * q2 + 4 * hi];
                float4 o;
                o.x = (oacc[mf][4 * q2 + 0] + o2[0]) * linv;
                o.y = (oacc[mf][4 * q2 + 1] + o2[1]) * linv;
                o.z = (oacc[mf][4 * q2 + 2] + o2[2]) * linv;
                o.w = (oacc[mf][4 * q2 + 3] + o2[3]) * linv;
                *(float4*)(dst + 32 * mf + 8 * q2 + 4 * hi) = o;
            }
    }
}

extern "C" void kernel_launch(void* const* d_in, const int* in_sizes, int n_in,
                              void* d_out, int out_size, void* d_ws, size_t ws_size,
                              hipStream_t stream) {
    (void)in_sizes; (void)n_in; (void)out_size; (void)ws_size;
    const float* q = (const float*)d_in[0];
    const float* k = (const float*)d_in[1];
    const float* v = (const float*)d_in[2];
    const int* perm = (const int*)d_in[3];
    float* out = (float*)d_out;
    char* kw = (char*)d_ws;          // 4MB
    char* vtw = kw + 8 * BB;         // 4MB
    hipLaunchKernelGGL(hilbert_prepass_kernel, dim3(512), dim3(256), 0, stream,
                       k, v, perm, kw, vtw);
    hipLaunchKernelGGL(hilbert_attn_kernel, dim3(256), dim3(512), 0, stream,
                       q, perm, kw, vtw, out);
}

// Round 22
// 50.365 us; speedup vs baseline: 1.1348x; 1.0768x over previous
//
#include <hip/hip_runtime.h>

typedef _Float16 f16;
typedef _Float16 f16x4 __attribute__((ext_vector_type(4)));
typedef _Float16 f16x8 __attribute__((ext_vector_type(8)));
typedef __fp16 fp16x2 __attribute__((ext_vector_type(2)));   // cvt_pkrtz native type
typedef float f32x4 __attribute__((ext_vector_type(4)));

#define MFMA_16x16x32_F16(A, B, C) __builtin_amdgcn_mfma_f32_16x16x32_f16((A), (B), (C), 0, 0, 0)

typedef const __attribute__((address_space(1))) char gchar;
typedef __attribute__((address_space(3))) char lchar;

__device__ __forceinline__ float fexp2(float x) { return __builtin_amdgcn_exp2f(x); }
__device__ __forceinline__ int swzb(int b) { return b ^ ((b >> 3) & 0x70); }  // involution, 8KB-tile-local

namespace {
constexpr int SB = 4096;                       // tokens per flattened batch = 64 tiles of 64
constexpr size_t BB = (size_t)SB * 64 * 2;     // f16 bytes per batch per tensor = 512KB
}

// V-ONLY token permutation within each 64-token tile (K stays identity!):
//   V^T stored slot n holds token kappa_V(n), kappa_V(32kt+8g+4a+v)=32kt+16a+4g+v.
//   PV's B-fragment slot 32kt+8g+j then needs exactly the lane's own QK^T output
//   e[8kt+j], so P never leaves registers.
__device__ __forceinline__ int kinv(int r) {
    return 32 * (r >> 5) + 8 * ((r >> 2) & 3) + 4 * ((r >> 4) & 1) + (r & 3);
}

// ---------------- pre-pass: gather + fp16 convert + V tile-transpose ----------------
// Stores PRE-SWIZZLED within each 8KB tile; V additionally kappa_V-permuted in token axis.
__global__ __launch_bounds__(256)
void hilbert_prepass_kernel(const float* __restrict__ kp, const float* __restrict__ vp,
                            const int* __restrict__ perm,
                            char* __restrict__ kw, char* __restrict__ vtw)
{
    const int bid = blockIdx.x;
    const int batch = bid & 7;
    const int tile = bid >> 3;
    const int tid = (int)threadIdx.x;
    const int r = tid >> 2;       // token in tile
    const int c4 = tid & 3;       // 16-dim quarter

    __shared__ float Vl[64][68];  // fp32 V tile, padded

    const int t = tile * 64 + r;
    const int srow = perm[batch * 512 + (t >> 3)];
    const size_t boff = (size_t)srow * 512 + (t & 7) * 64 + c4 * 16;

    {   // K -> fp16, IDENTITY row placement, swizzled store
        const float* ks = kp + boff;
        const float4 k0 = *(const float4*)(ks + 0);
        const float4 k1 = *(const float4*)(ks + 4);
        const float4 k2 = *(const float4*)(ks + 8);
        const float4 k3 = *(const float4*)(ks + 12);
        f16x8 h0, h1;
        h0[0] = (f16)k0.x; h0[1] = (f16)k0.y; h0[2] = (f16)k0.z; h0[3] = (f16)k0.w;
        h0[4] = (f16)k1.x; h0[5] = (f16)k1.y; h0[6] = (f16)k1.z; h0[7] = (f16)k1.w;
        h1[0] = (f16)k2.x; h1[1] = (f16)k2.y; h1[2] = (f16)k2.z; h1[3] = (f16)k2.w;
        h1[4] = (f16)k3.x; h1[5] = (f16)k3.y; h1[6] = (f16)k3.z; h1[7] = (f16)k3.w;
        char* kt = kw + (size_t)batch * BB + (size_t)tile * 8192;
        const int o = r * 128 + c4 * 32;
        *(f16x8*)(kt + swzb(o)) = h0;
        *(f16x8*)(kt + swzb(o + 16)) = h1;
    }
    {   // V fp32 -> LDS
        const float* vs = vp + boff;
        *(float4*)&Vl[r][c4 * 16 + 0]  = *(const float4*)(vs + 0);
        *(float4*)&Vl[r][c4 * 16 + 4]  = *(const float4*)(vs + 4);
        *(float4*)&Vl[r][c4 * 16 + 8]  = *(const float4*)(vs + 8);
        *(float4*)&Vl[r][c4 * 16 + 12] = *(const float4*)(vs + 12);
    }
    __syncthreads();
    {   // transpose out of LDS: thread owns dim d, tokens 16a..16a+15; kappa_V cols
        const int d = tid >> 2;
        const int a = tid & 3;
        char* vt = vtw + (size_t)batch * BB + (size_t)tile * 8192;
        const int b0 = 32 * (a >> 1) + 4 * (a & 1);
#pragma unroll
        for (int gp = 0; gp < 4; ++gp) {
            f16x4 qv;
#pragma unroll
            for (int v = 0; v < 4; ++v) qv[v] = (f16)Vl[16 * a + 4 * gp + v][d];
            *(f16x4*)(vt + swzb(d * 128 + (b0 + 8 * gp) * 2)) = qv;
        }
    }
}

// ---------------- main attention ----------------
// 256 blocks (1/CU) x 512 threads = 8 waves (proven-best r14 configuration).
// Wave = (wq, half): q-slot wq owns 32 q-rows (two 16-row subtiles sharing every
// K/V fragment read); half splits KV tiles even/odd. NO-MAX softmax; P in regs.
// T4 counted-vmcnt pipeline (never vmcnt(0) in-loop):
//   issue Kn(2) -> QK -> issue Vn(2) -> softmax -> [vmcnt(4)+s_barrier: Vcur
//   confirmed, Kn/Vn IN FLIGHT] -> PV -> [vmcnt(2)+s_barrier: Kn confirmed,
//   Vn in flight]. Tail iteration peeled with vmcnt(0).
// LDS (64KB): two 32KB buffers {2 K-tiles | 2 Vt-tiles}; epilogue reuses as merge.
__global__ __launch_bounds__(512, 2)
void hilbert_attn_kernel(const float* __restrict__ qp,
                         const int* __restrict__ perm,
                         const char* __restrict__ kw, const char* __restrict__ vtw,
                         float* __restrict__ op)
{
    __shared__ __align__(16) char SM[65536];

    const int bid = blockIdx.x;
    const int batch = bid & 7;            // XCD-affine: one batch per XCD
    const int qbase = (bid >> 3) * 128;
    const int tid = (int)threadIdx.x;
    const int w = tid >> 6;
    const int lane = tid & 63;
    const int l16 = lane & 15;
    const int g = lane >> 4;
    const int half = w >> 2;
    const int wq = w & 3;
    const int swz = (l16 & 7) << 4;

    // Q B-fragments for both 16-row slots; scale*log2e folded
    f16x8 Qf0[2], Qf1[2];
    {
        constexpr float qscl = 0.125f * 1.44269504088896340736f;
#pragma unroll
        for (int s = 0; s < 2; ++s) {
            const int t = qbase + wq * 32 + s * 16 + l16;
            const int srow = perm[batch * 512 + (t >> 3)];
            const float* src = qp + (size_t)srow * 512 + (t & 7) * 64 + g * 8;
#pragma unroll
            for (int kt = 0; kt < 2; ++kt) {
                const float4 x0 = *(const float4*)(src + 32 * kt);
                const float4 x1 = *(const float4*)(src + 32 * kt + 4);
                f16x8 f;
                f[0] = (f16)(x0.x * qscl); f[1] = (f16)(x0.y * qscl);
                f[2] = (f16)(x0.z * qscl); f[3] = (f16)(x0.w * qscl);
                f[4] = (f16)(x1.x * qscl); f[5] = (f16)(x1.y * qscl);
                f[6] = (f16)(x1.z * qscl); f[7] = (f16)(x1.w * qscl);
                if (s == 0) Qf0[kt] = f; else Qf1[kt] = f;
            }
        }
    }

    f32x4 oacc0[4], oacc1[4];
#pragma unroll
    for (int i = 0; i < 4; ++i) {
        oacc0[i] = (f32x4){0.f, 0.f, 0.f, 0.f};
        oacc1[i] = (f32x4){0.f, 0.f, 0.f, 0.f};
    }
    float lr0 = 0.f, lr1 = 0.f;

    const char* ksrc = kw + (size_t)batch * BB + (size_t)tid * 16;
    const char* vsrc = vtw + (size_t)batch * BB + (size_t)tid * 16;

    union U8 { f16x8 v; fp16x2 h[4]; };

    {   // prologue: stage tile-pair 0 (2K + 2V = 32KB) into buffer 0, drain once
        lchar* dst = (lchar*)&SM[w << 10];
        __builtin_amdgcn_global_load_lds((gchar*)(ksrc), dst, 16, 0, 0);
        __builtin_amdgcn_global_load_lds((gchar*)(ksrc + 8192), dst + 8192, 16, 0, 0);
        __builtin_amdgcn_global_load_lds((gchar*)(vsrc), dst + 16384, 16, 0, 0);
        __builtin_amdgcn_global_load_lds((gchar*)(vsrc + 8192), dst + 24576, 16, 0, 0);
    }
    asm volatile("s_waitcnt vmcnt(0)" ::: "memory");
    __builtin_amdgcn_s_barrier();

    for (int it = 0; it < 31; ++it) {
        const int cur = it & 1;
        const int kbb = cur * 32768 + half * 8192;
        const int vbb = cur * 32768 + 16384 + half * 8192;
        const size_t go = (size_t)(it + 1) * 16384;
        lchar* dstb = (lchar*)&SM[(cur ^ 1) * 32768 + (w << 10)];

        // issue K(next) — stays in flight across the mid barrier
        __builtin_amdgcn_global_load_lds((gchar*)(ksrc + go), dstb, 16, 0, 0);
        __builtin_amdgcn_global_load_lds((gchar*)(ksrc + go + 8192), dstb + 8192, 16, 0, 0);

        // ---- S^T = K * Q^T for both q-slots, K fragments read ONCE ----
        f32x4 sa0[4], sa1[4];
#pragma unroll
        for (int i = 0; i < 4; ++i) {
            sa0[i] = (f32x4){0.f, 0.f, 0.f, 0.f};
            sa1[i] = (f32x4){0.f, 0.f, 0.f, 0.f};
        }
        __builtin_amdgcn_s_setprio(1);
#pragma unroll
        for (int kt = 0; kt < 2; ++kt) {
#pragma unroll
            for (int mt = 0; mt < 4; ++mt) {
                const int off = kbb + (l16 + 16 * mt) * 128 + (((g + 4 * kt) * 16) ^ swz);
                const f16x8 kf = *(const f16x8*)&SM[off];
                sa0[mt] = MFMA_16x16x32_F16(kf, Qf0[kt], sa0[mt]);
                sa1[mt] = MFMA_16x16x32_F16(kf, Qf1[kt], sa1[mt]);
            }
        }
        __builtin_amdgcn_s_setprio(0);

        // issue V(next) — confirmed at NEXT iter's mid barrier
        __builtin_amdgcn_global_load_lds((gchar*)(vsrc + go), dstb + 16384, 16, 0, 0);
        __builtin_amdgcn_global_load_lds((gchar*)(vsrc + go + 8192), dstb + 24576, 16, 0, 0);

        // ---- no-max softmax, P packed straight to registers (V-kappa layout) ----
        U8 p0k0, p0k1, p1k0, p1k1;
#pragma unroll
        for (int mt = 0; mt < 4; ++mt) {
            const float a0 = fexp2(sa0[mt][0]);
            const float a1 = fexp2(sa0[mt][1]);
            const float a2 = fexp2(sa0[mt][2]);
            const float a3 = fexp2(sa0[mt][3]);
            lr0 += (a0 + a1) + (a2 + a3);
            const float b0 = fexp2(sa1[mt][0]);
            const float b1 = fexp2(sa1[mt][1]);
            const float b2 = fexp2(sa1[mt][2]);
            const float b3 = fexp2(sa1[mt][3]);
            lr1 += (b0 + b1) + (b2 + b3);
            // e[4mt+v]; pack order: pXk0.h[i]=pack(e[2i],e[2i+1]), pXk1.h[i]=pack(e[8+2i],e[9+2i])
            if (mt < 2) {
                p0k0.h[2 * mt]     = __builtin_amdgcn_cvt_pkrtz(a0, a1);
                p0k0.h[2 * mt + 1] = __builtin_amdgcn_cvt_pkrtz(a2, a3);
                p1k0.h[2 * mt]     = __builtin_amdgcn_cvt_pkrtz(b0, b1);
                p1k0.h[2 * mt + 1] = __builtin_amdgcn_cvt_pkrtz(b2, b3);
            } else {
                p0k1.h[2 * (mt - 2)]     = __builtin_amdgcn_cvt_pkrtz(a0, a1);
                p0k1.h[2 * (mt - 2) + 1] = __builtin_amdgcn_cvt_pkrtz(a2, a3);
                p1k1.h[2 * (mt - 2)]     = __builtin_amdgcn_cvt_pkrtz(b0, b1);
                p1k1.h[2 * (mt - 2) + 1] = __builtin_amdgcn_cvt_pkrtz(b2, b3);
            }
        }

        // ---- mid barrier: V(cur) confirmed; K(next)/V(next) stay in flight ----
        // outstanding: [Vcur 2][Kn 2][Vn 2] = 6 -> wait to 4 drains Vcur only (it=0: 4, no-op)
        asm volatile("s_waitcnt vmcnt(4)" ::: "memory");
        __builtin_amdgcn_s_barrier();

        // ---- O^T += V^T * P^T, V fragments read ONCE for both slots ----
        __builtin_amdgcn_s_setprio(1);
#pragma unroll
        for (int kt = 0; kt < 2; ++kt) {
            const f16x8 pf0 = kt ? p0k1.v : p0k0.v;
            const f16x8 pf1 = kt ? p1k1.v : p1k0.v;
#pragma unroll
            for (int mtd = 0; mtd < 4; ++mtd) {
                const int voff = vbb + (l16 + 16 * mtd) * 128 + (((g + 4 * kt) * 16) ^ swz);
                const f16x8 vf = *(const f16x8*)&SM[voff];
                oacc0[mtd] = MFMA_16x16x32_F16(vf, pf0, oacc0[mtd]);
                oacc1[mtd] = MFMA_16x16x32_F16(vf, pf1, oacc1[mtd]);
            }
        }
        __builtin_amdgcn_s_setprio(0);

        // ---- end barrier: K(next) confirmed; V(next) stays in flight ----
        asm volatile("s_waitcnt vmcnt(2)" ::: "memory");
        __builtin_amdgcn_s_barrier();
    }

    {   // ---- tail iteration it=31 (buffer 1; outstanding at entry: [V31 2]) ----
        const int kbb = 32768 + half * 8192;
        const int vbb = 32768 + 16384 + half * 8192;

        f32x4 sa0[4], sa1[4];
#pragma unroll
        for (int i = 0; i < 4; ++i) {
            sa0[i] = (f32x4){0.f, 0.f, 0.f, 0.f};
            sa1[i] = (f32x4){0.f, 0.f, 0.f, 0.f};
        }
#pragma unroll
        for (int kt = 0; kt < 2; ++kt) {
#pragma unroll
            for (int mt = 0; mt < 4; ++mt) {
                const int off = kbb + (l16 + 16 * mt) * 128 + (((g + 4 * kt) * 16) ^ swz);
                const f16x8 kf = *(const f16x8*)&SM[off];
                sa0[mt] = MFMA_16x16x32_F16(kf, Qf0[kt], sa0[mt]);
                sa1[mt] = MFMA_16x16x32_F16(kf, Qf1[kt], sa1[mt]);
            }
        }
        U8 p0k0, p0k1, p1k0, p1k1;
#pragma unroll
        for (int mt = 0; mt < 4; ++mt) {
            const float a0 = fexp2(sa0[mt][0]);
            const float a1 = fexp2(sa0[mt][1]);
            const float a2 = fexp2(sa0[mt][2]);
            const float a3 = fexp2(sa0[mt][3]);
            lr0 += (a0 + a1) + (a2 + a3);
            const float b0 = fexp2(sa1[mt][0]);
            const float b1 = fexp2(sa1[mt][1]);
            const float b2 = fexp2(sa1[mt][2]);
            const float b3 = fexp2(sa1[mt][3]);
            lr1 += (b0 + b1) + (b2 + b3);
            if (mt < 2) {
                p0k0.h[2 * mt]     = __builtin_amdgcn_cvt_pkrtz(a0, a1);
                p0k0.h[2 * mt + 1] = __builtin_amdgcn_cvt_pkrtz(a2, a3);
                p1k0.h[2 * mt]     = __builtin_amdgcn_cvt_pkrtz(b0, b1);
                p1k0.h[2 * mt + 1] = __builtin_amdgcn_cvt_pkrtz(b2, b3);
            } else {
                p0k1.h[2 * (mt - 2)]     = __builtin_amdgcn_cvt_pkrtz(a0, a1);
                p0k1.h[2 * (mt - 2) + 1] = __builtin_amdgcn_cvt_pkrtz(a2, a3);
                p1k1.h[2 * (mt - 2)]     = __builtin_amdgcn_cvt_pkrtz(b0, b1);
                p1k1.h[2 * (mt - 2) + 1] = __builtin_amdgcn_cvt_pkrtz(b2, b3);
            }
        }
        asm volatile("s_waitcnt vmcnt(0)" ::: "memory");
        __builtin_amdgcn_s_barrier();
#pragma unroll
        for (int kt = 0; kt < 2; ++kt) {
            const f16x8 pf0 = kt ? p0k1.v : p0k0.v;
            const f16x8 pf1 = kt ? p1k1.v : p1k0.v;
#pragma unroll
            for (int mtd = 0; mtd < 4; ++mtd) {
                const int voff = vbb + (l16 + 16 * mtd) * 128 + (((g + 4 * kt) * 16) ^ swz);
                const f16x8 vf = *(const f16x8*)&SM[voff];
                oacc0[mtd] = MFMA_16x16x32_F16(vf, pf0, oacc0[mtd]);
                oacc1[mtd] = MFMA_16x16x32_F16(vf, pf1, oacc1[mtd]);
            }
        }
    }

    // ---- reduce l across the 4 key-groups of each wave ----
    lr0 += __shfl_xor(lr0, 16);
    lr0 += __shfl_xor(lr0, 32);
    lr1 += __shfl_xor(lr1, 16);
    lr1 += __shfl_xor(lr1, 32);

    __syncthreads();   // loop done; reuse SM for merge

    // ---- merge wave pairs (w, w+4): l = la+lb, O = Oa+Ob ----
    float* OB = (float*)SM;                 // 4 pairs x 8KB (32 rows x 64 dims)
    float* ML = (float*)&SM[32768];         // 4 pairs x 32 l-values
    if (w >= 4) {
        float* ob = OB + wq * 2048;
#pragma unroll
        for (int mtd = 0; mtd < 4; ++mtd) {
            *(f32x4*)&ob[l16 * 64 + mtd * 16 + g * 4] = oacc0[mtd];
            *(f32x4*)&ob[(16 + l16) * 64 + mtd * 16 + g * 4] = oacc1[mtd];
        }
        if (g == 0) {
            ML[wq * 32 + l16] = lr0;
            ML[wq * 32 + 16 + l16] = lr1;
        }
    }
    __syncthreads();
    if (w < 4) {
        float* ob = OB + wq * 2048;
#pragma unroll
        for (int s = 0; s < 2; ++s) {
            const float lmine = (s == 0) ? lr0 : lr1;
            const float linv = 1.f / (lmine + ML[wq * 32 + s * 16 + l16]);
            const int t = qbase + wq * 32 + s * 16 + l16;
            const int srow = perm[t];       // scatter uses FULL-t perm (round-1 lesson)
            float* dst = op + (size_t)srow * 512 + batch * 64 + 4 * g;
#pragma unroll
            for (int mtd = 0; mtd < 4; ++mtd) {
                const f32x4 mine = (s == 0) ? oacc0[mtd] : oacc1[mtd];
                const f32x4 o2 = *(const f32x4*)&ob[(s * 16 + l16) * 64 + mtd * 16 + g * 4];
                float4 o;
                o.x = (mine[0] + o2[0]) * linv;
                o.y = (mine[1] + o2[1]) * linv;
                o.z = (mine[2] + o2[2]) * linv;
                o.w = (mine[3] + o2[3]) * linv;
                *(float4*)(dst + 16 * mtd) = o;
            }
        }
    }
}

extern "C" void kernel_launch(void* const* d_in, const int* in_sizes, int n_in,
                              void* d_out, int out_size, void* d_ws, size_t ws_size,
                              hipStream_t stream) {
    (void)in_sizes; (void)n_in; (void)out_size; (void)ws_size;
    const float* q = (const float*)d_in[0];
    const float* k = (const float*)d_in[1];
    const float* v = (const float*)d_in[2];
    const int* perm = (const int*)d_in[3];
    float* out = (float*)d_out;
    char* kw = (char*)d_ws;          // 4MB
    char* vtw = kw + 8 * BB;         // 4MB
    hipLaunchKernelGGL(hilbert_prepass_kernel, dim3(512), dim3(256), 0, stream,
                       k, v, perm, kw, vtw);
    hipLaunchKernelGGL(hilbert_attn_kernel, dim3(256), dim3(512), 0, stream,
                       q, perm, kw, vtw, out);
}